// Round 8
// baseline (722.580 us; speedup 1.0000x reference)
//
#include <hip/hip_runtime.h>

typedef __bf16 bf16;
typedef __bf16 bf16x8 __attribute__((ext_vector_type(8)));
typedef __bf16 bf16x4 __attribute__((ext_vector_type(4)));
typedef float  f32x4  __attribute__((ext_vector_type(4)));

// ---------------------------------------------------------------------------
// f32 -> bf16 convert, 4-wide
// ---------------------------------------------------------------------------
__global__ void f2b_kernel(const float* __restrict__ src, bf16* __restrict__ dst, int n4) {
    int i = blockIdx.x * 256 + threadIdx.x;
    if (i >= n4) return;
    float4 v = ((const float4*)src)[i];
    bf16x4 o = { (bf16)v.x, (bf16)v.y, (bf16)v.z, (bf16)v.w };
    ((bf16x4*)dst)[i] = o;
}

// ---------------------------------------------------------------------------
// Swizzle fp32 W (taps, cin, cout) into bf16 MFMA-B-fragment order:
//   Wf[tap][s][nt][lane][j] = W[tap][s*32 + (lane>>4)*8 + j][nt*16 + (lane&15)]
// ---------------------------------------------------------------------------
__global__ void swz_kernel(const float* __restrict__ W, bf16* __restrict__ Wf,
                           int cin, int cout, int total) {
    int e = blockIdx.x * 256 + threadIdx.x;
    if (e >= total) return;
    int per_tap = cin * cout;
    int tap = e / per_tap;
    int t2  = e - tap * per_tap;
    int ntc = cout >> 4;               // number of 16-col tiles
    int s   = t2 / (ntc * 512);        // K-step of 32
    int r3  = t2 - s * (ntc * 512);
    int nt  = r3 >> 9;
    int L   = (r3 & 511) >> 3;
    int j   = r3 & 7;
    int k   = s * 32 + (L >> 4) * 8 + j;
    int col = nt * 16 + (L & 15);
    Wf[e] = (bf16)W[((size_t)tap * cin + k) * cout + col];
}

// ---------------------------------------------------------------------------
// ROUND-8 STRUCTURE: R5 (verified tap-split, barrier-free main loop) with
// BOTH occupancy limiters lifted:
//  - LDS: NP-pass cross-wave reduction, NP=4 where WC1>=4 (2 for C1=32 --
//    R7's CPF=0 bug: 2/4=0 emptied the reduce loops for the b3 layer).
//    ~43KB -> ~26KB per block.
//  - VGPR: R5 totals ~132/wave (68 arch + 64 acc) -> 3 waves/SIMD. Drop the
//    B-fragment double-buffer; load B per 2-column group INSIDE the MFMA
//    loop (live B 32->16 regs; B is L2-hot, latency hides under MFMA chain
//    + extra waves). Keep A depth-1 prefetch (the long-latency gather).
//    launch_bounds(256,4) enforces <=128 total -> 4 waves/SIMD.
// setprio(1) kept around the MFMA cluster (independent-phase waves).
// ---------------------------------------------------------------------------
template<int CIN, int C1, int TAPS, int C2, int C3>
__global__ __launch_bounds__(256, 4) void layer_kernel(
    const bf16* __restrict__ X,
    const bf16* __restrict__ W1,     // swizzled (TAPS*CIN/32, C1/16, 512)
    const bf16* __restrict__ W2,     // swizzled (C1/32, C2/16, 512)
    const bf16* __restrict__ W3,     // swizzled (C2/32, C3/16, 512) or null
    const int*  __restrict__ nbr,    // (TAPS, n)
    const float* __restrict__ sc1, const float* __restrict__ sh1,
    const float* __restrict__ sc2, const float* __restrict__ sh2,
    const float* __restrict__ sc3, const float* __restrict__ sh3,
    bf16* __restrict__ Y, float* __restrict__ Yf,
    int ystride, int yoff, int n, int nblocks)
{
    constexpr int NT1 = C1 / 16;
    constexpr int WC1 = NT1;                 // wave covers full output width
    constexpr int RW  = (C1 >= 128) ? 32 : 64;   // rows per block tile
    constexpr int WR1 = RW / 16;             // row fragments per wave
    constexpr int KS  = CIN / 32;            // K-slices per tap
    constexpr int LS1 = C1 + 8;
    constexpr int LS2 = C2 + 8;
    // NP-pass reduction geometry (NP=4 halves PRB vs 2-pass; NP=2 if WC1<4)
    constexpr int NP  = (WC1 >= 4) ? 4 : 2;  // column passes
    constexpr int CPF = WC1 / NP;            // col-fragments per pass (>=1)
    constexpr int CP  = 16 * CPF;            // columns per pass
    constexpr int CPS = CP + 1;              // padded stride
    constexpr int PRB = 4 * RW * CPS * 4;    // partial buffer bytes
    constexpr int LTB = RW * LS1 * 2;

    __shared__ __align__(16) char smem[PRB + LTB];
    float* PR  = (float*)smem;               // 4 x RW x CPS f32 partials
    bf16*  Lt  = (bf16*)(smem + PRB);        // h1 tile (RW x LS1)
    bf16*  Lt2 = (bf16*)smem;                // h2 tile, aliases PR (PR dead)

    const int tid  = threadIdx.x;
    const int lane = tid & 63;
    const int wv   = tid >> 6;
    const int m16  = lane & 15;
    const int quad = lane >> 4;

    // XCD-contiguous block swizzle (bijection, m204 form)
    const int bq = nblocks >> 3, br = nblocks & 7;
    const int bx = blockIdx.x & 7, bs = blockIdx.x >> 3;
    const int sb = bx * bq + (bx < br ? bx : br) + bs;
    const int base = sb * RW;

    // this wave's tap range (7/7/7/6 for TAPS=27)
    constexpr int TB = TAPS / 4, TR = TAPS % 4;
    const int tstart = wv * TB + (wv < TR ? wv : TR);
    const int tcnt   = TB + (wv < TR ? 1 : 0);
    const int TOTW   = tcnt * KS;

    const bf16x8 ZB = __builtin_bit_cast(bf16x8, (float4){0.f, 0.f, 0.f, 0.f});

    int idxc[WR1], idxn[WR1];
    auto load_idx = [&](int t, int (&id)[WR1]) {
#pragma unroll
        for (int r = 0; r < WR1; ++r)
            id[r] = nbr[(size_t)t * n + base + r * 16 + m16];
    };

    f32x4 acc1[WR1][WC1];
#pragma unroll
    for (int r = 0; r < WR1; ++r)
#pragma unroll
        for (int c = 0; c < WC1; ++c) acc1[r][c] = (f32x4){0.f, 0.f, 0.f, 0.f};

    bf16x8 aA[WR1], aB[WR1];

    // prologue: gather step 0; indices for first two taps
    load_idx(tstart, idxc);
    if (tcnt > 1) load_idx(tstart + 1, idxn);
#pragma unroll
    for (int r = 0; r < WR1; ++r) {
        bf16x8 v = ZB;
        if (idxc[r] >= 0) v = *(const bf16x8*)(X + (size_t)(unsigned)idxc[r] * CIN + quad * 8);
        aA[r] = v;
    }

    int tloc = 0, s = 0;
    auto dostep = [&](int it, bf16x8 (&aC)[WR1], bf16x8 (&aN)[WR1]) {
        int s1 = s + 1, tl1 = tloc;
        bool wrap = (s1 == KS);
        if (wrap) { s1 = 0; ++tl1; }
        if (it + 1 < TOTW) {
#pragma unroll
            for (int r = 0; r < WR1; ++r) {          // next-step gather (depth-1)
                int id_ = wrap ? idxn[r] : idxc[r];
                bf16x8 v = ZB;
                if (id_ >= 0) v = *(const bf16x8*)(X + (size_t)(unsigned)id_ * CIN + s1 * 32 + quad * 8);
                aN[r] = v;
            }
        }
        // B-fragments loaded per 2-column group inside the MFMA loop (low live regs)
        const bf16* wt = W1 + (size_t)((tstart + tloc) * KS + s) * (NT1 * 512) + lane * 8;
        __builtin_amdgcn_s_setprio(1);
#pragma unroll
        for (int cg = 0; cg < WC1; cg += 2) {
            bf16x8 b0 = *(const bf16x8*)(wt + cg * 512);
            bf16x8 b1 = *(const bf16x8*)(wt + (cg + 1) * 512);
#pragma unroll
            for (int r = 0; r < WR1; ++r)
                acc1[r][cg]     = __builtin_amdgcn_mfma_f32_16x16x32_bf16(aC[r], b0, acc1[r][cg], 0, 0, 0);
#pragma unroll
            for (int r = 0; r < WR1; ++r)
                acc1[r][cg + 1] = __builtin_amdgcn_mfma_f32_16x16x32_bf16(aC[r], b1, acc1[r][cg + 1], 0, 0, 0);
        }
        __builtin_amdgcn_s_setprio(0);
        if (wrap) {
#pragma unroll
            for (int r = 0; r < WR1; ++r) idxc[r] = idxn[r];
            if (tloc + 2 < tcnt) load_idx(tstart + tloc + 2, idxn);
        }
        tloc = tl1; s = s1;
    };

    for (int it = 0; it < TOTW; it += 2) {
        dostep(it, aA, aB);
        if (it + 1 < TOTW) dostep(it + 1, aB, aA);
    }

    // ---- cross-wave tap reduction (NP column passes) -> bnrelu -> Lt ----
    constexpr int SLICE = RW / 4;            // rows summed per wave
#pragma unroll
    for (int p = 0; p < NP; ++p) {
        __syncthreads();                     // converge / WAR on PR
        float* Pw = PR + wv * (RW * CPS);
#pragma unroll
        for (int c = 0; c < CPF; ++c)
#pragma unroll
            for (int r = 0; r < WR1; ++r)
#pragma unroll
                for (int i = 0; i < 4; ++i)
                    Pw[(r * 16 + quad * 4 + i) * CPS + c * 16 + m16] = acc1[r][p * CPF + c][i];
        __syncthreads();
#pragma unroll
        for (int e = lane; e < SLICE * CP; e += 64) {
            int row  = wv * SLICE + e / CP;
            int colh = e & (CP - 1);
            float v = PR[(0 * RW + row) * CPS + colh] + PR[(1 * RW + row) * CPS + colh]
                    + PR[(2 * RW + row) * CPS + colh] + PR[(3 * RW + row) * CPS + colh];
            int col = p * CP + colh;
            v = v * sc1[col] + sh1[col];
            v = v > 0.f ? v : 0.f;
            Lt[row * LS1 + col] = (bf16)v;
        }
    }
    __syncthreads();                         // Lt complete

    // ---- dense stage 2: wave -> (row group, col group) ----
    constexpr int NT2  = C2 / 16;
    constexpr int DRW  = RW / 16 >= 4 ? 4 : RW / 16;  // 4 (RW=64) or 2 (RW=32)
    constexpr int NCG  = 4 / DRW;                     // col groups: 1 or 2
    constexpr int WC2g = NT2 / NCG;
    constexpr int KS2  = C1 / 32;
    const int wr  = wv % DRW;
    const int wcg = wv / DRW;

    f32x4 acc2[WC2g];
#pragma unroll
    for (int c = 0; c < WC2g; ++c) acc2[c] = (f32x4){0.f, 0.f, 0.f, 0.f};

#pragma unroll
    for (int s2 = 0; s2 < KS2; ++s2) {
        bf16x8 a = *(const bf16x8*)(&Lt[(wr * 16 + m16) * LS1 + s2 * 32 + quad * 8]);
        bf16x8 bw[WC2g];
#pragma unroll
        for (int c = 0; c < WC2g; ++c)
            bw[c] = *(const bf16x8*)(W2 + ((s2 * NT2 + wcg * WC2g + c) * 512 + lane * 8));
#pragma unroll
        for (int c = 0; c < WC2g; ++c)
            acc2[c] = __builtin_amdgcn_mfma_f32_16x16x32_bf16(a, bw[c], acc2[c], 0, 0, 0);
    }

    if constexpr (C3 == 0) {
#pragma unroll
        for (int c = 0; c < WC2g; ++c) {
            int col = (wcg * WC2g + c) * 16 + m16;
            float sc = sc2[col], sh = sh2[col];
            int row0 = base + wr * 16 + quad * 4;
#pragma unroll
            for (int i = 0; i < 4; ++i) {
                float v = acc2[c][i] * sc + sh;
                v = v > 0.f ? v : 0.f;
                size_t off = (size_t)(row0 + i) * ystride + yoff + col;
                if (Yf) Yf[off] = v;
                else    Y[off] = (bf16)v;
            }
        }
    } else {
        // ---- stage-2 epilogue -> Lt2 (aliases dead PR region) ----
#pragma unroll
        for (int c = 0; c < WC2g; ++c) {
            int col = (wcg * WC2g + c) * 16 + m16;
            float sc = sc2[col], sh = sh2[col];
            int row0 = wr * 16 + quad * 4;
#pragma unroll
            for (int i = 0; i < 4; ++i) {
                float v = acc2[c][i] * sc + sh;
                v = v > 0.f ? v : 0.f;
                Lt2[(row0 + i) * LS2 + col] = (bf16)v;
            }
        }
        __syncthreads();                     // Lt2 complete

        constexpr int C3v  = (C3 > 0) ? C3 : 16;
        constexpr int NT3  = C3v / 16;
        constexpr int WC3g = NT3 / NCG;
        constexpr int KS3  = C2 / 32;

        f32x4 acc3[WC3g];
#pragma unroll
        for (int c = 0; c < WC3g; ++c) acc3[c] = (f32x4){0.f, 0.f, 0.f, 0.f};

#pragma unroll
        for (int s3 = 0; s3 < KS3; ++s3) {
            bf16x8 a = *(const bf16x8*)(&Lt2[(wr * 16 + m16) * LS2 + s3 * 32 + quad * 8]);
            bf16x8 bw[WC3g];
#pragma unroll
            for (int c = 0; c < WC3g; ++c)
                bw[c] = *(const bf16x8*)(W3 + ((s3 * NT3 + wcg * WC3g + c) * 512 + lane * 8));
#pragma unroll
            for (int c = 0; c < WC3g; ++c)
                acc3[c] = __builtin_amdgcn_mfma_f32_16x16x32_bf16(a, bw[c], acc3[c], 0, 0, 0);
        }

#pragma unroll
        for (int c = 0; c < WC3g; ++c) {
            int col = (wcg * WC3g + c) * 16 + m16;
            float sc = sc3[col], sh = sh3[col];
            int row0 = base + wr * 16 + quad * 4;
#pragma unroll
            for (int i = 0; i < 4; ++i) {
                float v = acc3[c][i] * sc + sh;
                v = v > 0.f ? v : 0.f;
                size_t off = (size_t)(row0 + i) * ystride + yoff + col;
                if (Yf) Yf[off] = v;
                else    Y[off] = (bf16)v;
            }
        }
    }
}

// ---------------------------------------------------------------------------
// z[:, 64:96] = sanitize(y2[align_idx])  (features_at_coordinates + concat)
// ---------------------------------------------------------------------------
__global__ void concat_kernel(const bf16* __restrict__ y2, const int* __restrict__ align,
                              bf16* __restrict__ z, int n) {
    int e = blockIdx.x * 256 + threadIdx.x;   // over n*32
    if (e >= n * 32) return;
    int i = e >> 5, c = e & 31;
    int a = align[i];
    float v = (float)y2[(size_t)a * 32 + c];
    unsigned u = __builtin_bit_cast(unsigned, v);
    if ((u & 0x7f800000u) == 0x7f800000u) v = 0.f;   // NaN/Inf -> 0
    z[(size_t)i * 96 + 64 + c] = (bf16)v;
}

// ---------------------------------------------------------------------------
extern "C" void kernel_launch(void* const* d_in, const int* in_sizes, int n_in,
                              void* d_out, int out_size, void* d_ws, size_t ws_size,
                              hipStream_t stream) {
    const float* feat3d = (const float*)d_in[0];
    const float* feat2d = (const float*)d_in[1];
    const float* Wsrc[11];
    for (int i = 0; i < 11; ++i) Wsrc[i] = (const float*)d_in[2 + i];
    const float* bn[22];
    for (int i = 0; i < 22; ++i) bn[i] = (const float*)d_in[13 + i];
    const int* nbr   = (const int*)d_in[35];
    const int* align = (const int*)d_in[36];
    float* out = (float*)d_out;

    const int n = in_sizes[0] / 96;   // 80000, divisible by 64 and 32

    // workspace layout
    char* ws = (char*)d_ws;
    size_t off = 0;
    auto alloc = [&](size_t bytes) -> void* {
        void* p = ws + off;
        off = (off + bytes + 255) & ~(size_t)255;
        return p;
    };
    bf16* F3 = (bf16*)alloc((size_t)n * 96 * 2);
    bf16* F2 = (bf16*)alloc((size_t)n * 256 * 2);
    static const int wt_taps[11] = {27, 1, 27, 1, 27, 1, 27, 1, 27, 1, 1};
    static const int wt_cin[11]  = {96, 64, 64, 64, 256, 64, 64, 32, 96, 128, 128};
    static const int wt_cout[11] = {64, 64, 64, 64, 64, 64, 32, 32, 128, 128, 128};
    bf16* Wf[11];
    for (int i = 0; i < 11; ++i)
        Wf[i] = (bf16*)alloc((size_t)wt_taps[i] * wt_cin[i] * wt_cout[i] * 2);
    bf16* tA = (bf16*)alloc((size_t)n * 64 * 2);
    bf16* tB = (bf16*)alloc((size_t)n * 64 * 2);
    bf16* y2 = (bf16*)alloc((size_t)n * 32 * 2);
    bf16* z  = (bf16*)alloc((size_t)n * 96 * 2);

    // ---- prep: converts + weight swizzles ----
    f2b_kernel<<<(n * 96 / 4 + 255) / 256, 256, 0, stream>>>(feat3d, F3, n * 96 / 4);
    f2b_kernel<<<(n * 256 / 4 + 255) / 256, 256, 0, stream>>>(feat2d, F2, n * 256 / 4);
    for (int i = 0; i < 11; ++i) {
        int total = wt_taps[i] * wt_cin[i] * wt_cout[i];
        swz_kernel<<<(total + 255) / 256, 256, 0, stream>>>(Wsrc[i], Wf[i], wt_cin[i], wt_cout[i], total);
    }

    const int GB64 = n / 64;   // 1250 blocks x 4 tap-split waves
    const int GB32 = n / 32;   // 2500 blocks (c-layer, RW=32)

    // ---- 3D branch: (a1+a2), (a3+a4) ----
    layer_kernel<96, 64, 27, 64, 0><<<GB64, 256, 0, stream>>>(
        F3, Wf[0], Wf[1], nullptr, nbr,
        bn[0], bn[1], bn[2], bn[3], nullptr, nullptr,
        tB, nullptr, 64, 0, n, GB64);
    layer_kernel<64, 64, 27, 64, 0><<<GB64, 256, 0, stream>>>(
        tB, Wf[2], Wf[3], nullptr, nbr,
        bn[4], bn[5], bn[6], bn[7], nullptr, nullptr,
        z, nullptr, 96, 0, n, GB64);               // x3 -> z[:,0:64]

    // ---- 2D branch: (b1+b2), (b3+b4) ----
    layer_kernel<256, 64, 27, 64, 0><<<GB64, 256, 0, stream>>>(
        F2, Wf[4], Wf[5], nullptr, nbr,
        bn[8], bn[9], bn[10], bn[11], nullptr, nullptr,
        tA, nullptr, 64, 0, n, GB64);
    layer_kernel<64, 32, 27, 32, 0><<<GB64, 256, 0, stream>>>(
        tA, Wf[6], Wf[7], nullptr, nbr,
        bn[12], bn[13], bn[14], bn[15], nullptr, nullptr,
        y2, nullptr, 32, 0, n, GB64);

    // ---- align gather + concat into z[:,64:96] ----
    concat_kernel<<<(n * 32 + 255) / 256, 256, 0, stream>>>(y2, align, z, n);

    // ---- fusion: (c1+c2+c3) ----
    layer_kernel<96, 128, 27, 128, 128><<<GB32, 256, 0, stream>>>(
        z, Wf[8], Wf[9], Wf[10], nbr,
        bn[16], bn[17], bn[18], bn[19], bn[20], bn[21],
        nullptr, out, 128, 0, n, GB32);
}

// Round 9
// 585.474 us; speedup vs baseline: 1.2342x; 1.2342x over previous
//
#include <hip/hip_runtime.h>

typedef __bf16 bf16;
typedef __bf16 bf16x8 __attribute__((ext_vector_type(8)));
typedef __bf16 bf16x4 __attribute__((ext_vector_type(4)));
typedef float  f32x4  __attribute__((ext_vector_type(4)));

// ---------------------------------------------------------------------------
// f32 -> bf16 convert, 4-wide
// ---------------------------------------------------------------------------
__global__ void f2b_kernel(const float* __restrict__ src, bf16* __restrict__ dst, int n4) {
    int i = blockIdx.x * 256 + threadIdx.x;
    if (i >= n4) return;
    float4 v = ((const float4*)src)[i];
    bf16x4 o = { (bf16)v.x, (bf16)v.y, (bf16)v.z, (bf16)v.w };
    ((bf16x4*)dst)[i] = o;
}

// ---------------------------------------------------------------------------
// Swizzle fp32 W (taps, cin, cout) into bf16 MFMA-B-fragment order:
//   Wf[tap][s][nt][lane][j] = W[tap][s*32 + (lane>>4)*8 + j][nt*16 + (lane&15)]
// ---------------------------------------------------------------------------
__global__ void swz_kernel(const float* __restrict__ W, bf16* __restrict__ Wf,
                           int cin, int cout, int total) {
    int e = blockIdx.x * 256 + threadIdx.x;
    if (e >= total) return;
    int per_tap = cin * cout;
    int tap = e / per_tap;
    int t2  = e - tap * per_tap;
    int ntc = cout >> 4;               // number of 16-col tiles
    int s   = t2 / (ntc * 512);        // K-step of 32
    int r3  = t2 - s * (ntc * 512);
    int nt  = r3 >> 9;
    int L   = (r3 & 511) >> 3;
    int j   = r3 & 7;
    int k   = s * 32 + (L >> 4) * 8 + j;
    int col = nt * 16 + (L & 15);
    Wf[e] = (bf16)W[((size_t)tap * cin + k) * cout + col];
}

// ---------------------------------------------------------------------------
// ROUND-9: R5 (verified best) + the R8 lesson applied to the c-layer.
// R8 proved serial in-loop B loads cost ~50% (187us vs ~125, MfmaUtil 19->15
// despite higher occupancy). R5's c-layer (WC1=8 > BPRE limit) has had
// serial B loads all along AND 6.5GB of B-fragment re-reads (each 32-row
// block reads the full 128-col weight set). Fix: hybrid wave split for
// wide layers -- waves = (tap-group x col-group). NCG1=2 for C1=128 gives
// every wave WC1=4 col-frags: B traffic /4 and register double-buffered B
// (BPRE) everywhere; no serial B anywhere. Cross-wave reduction sums TW
// partials per column slot (R8-verified CPF=1 pass structure; PR shrinks).
// 64-row layers keep R5's exact main loop.
// ---------------------------------------------------------------------------
template<int CIN, int C1, int TAPS, int C2, int C3>
__global__ __launch_bounds__(256, 3) void layer_kernel(
    const bf16* __restrict__ X,
    const bf16* __restrict__ W1,     // swizzled (TAPS*CIN/32, C1/16, 512)
    const bf16* __restrict__ W2,     // swizzled (C1/32, C2/16, 512)
    const bf16* __restrict__ W3,     // swizzled (C2/32, C3/16, 512) or null
    const int*  __restrict__ nbr,    // (TAPS, n)
    const float* __restrict__ sc1, const float* __restrict__ sh1,
    const float* __restrict__ sc2, const float* __restrict__ sh2,
    const float* __restrict__ sc3, const float* __restrict__ sh3,
    bf16* __restrict__ Y, float* __restrict__ Yf,
    int ystride, int yoff, int n, int nblocks)
{
    constexpr int NT1  = C1 / 16;
    constexpr int NCG1 = (NT1 > 4) ? 2 : 1;      // col-groups of waves
    constexpr int WC1  = NT1 / NCG1;             // col-frags per wave (<=4)
    constexpr int TW   = 4 / NCG1;               // tap-split ways (2 or 4)
    constexpr int RW   = (C1 >= 128) ? 32 : 64;  // rows per block tile
    constexpr int WR1  = RW / 16;                // row frags per wave
    constexpr int KS   = CIN / 32;               // K-slices per tap
    constexpr int LS1  = C1 + 8;
    constexpr int LS2  = C2 + 8;
    // reduction: NP passes of 1 col-frag per wave (R8-verified structure)
    constexpr int NP   = WC1;                    // passes
    constexpr int CPT  = 16 * NCG1;              // distinct cols per pass
    constexpr int PCW  = CPT + 1;                // padded stride
    constexpr int PRB  = TW * RW * PCW * 4;      // partial buffer bytes
    constexpr int L2TB = (C3 > 0) ? RW * LS2 * 2 : 0;
    constexpr int REG  = (PRB > L2TB) ? PRB : L2TB;
    constexpr int LTB  = RW * LS1 * 2;

    __shared__ __align__(16) char smem[REG + LTB];
    float* PR  = (float*)smem;               // TW x RW x PCW f32 partials
    bf16*  Lt  = (bf16*)(smem + REG);        // h1 tile (RW x LS1)
    bf16*  Lt2 = (bf16*)smem;                // h2 tile, aliases PR (PR dead)

    const int tid  = threadIdx.x;
    const int lane = tid & 63;
    const int wv   = tid >> 6;
    const int m16  = lane & 15;
    const int quad = lane >> 4;
    const int tg   = wv % TW;                // tap group
    const int cg   = wv / TW;                // col group (0 or NCG1-1)

    // XCD-contiguous block swizzle (bijection, m204 form)
    const int bq = nblocks >> 3, br = nblocks & 7;
    const int bx = blockIdx.x & 7, bs = blockIdx.x >> 3;
    const int sb = bx * bq + (bx < br ? bx : br) + bs;
    const int base = sb * RW;

    // this wave's tap range over TW groups
    constexpr int TB = TAPS / TW, TR = TAPS % TW;
    const int tstart = tg * TB + (tg < TR ? tg : TR);
    const int tcnt   = TB + (tg < TR ? 1 : 0);
    const int TOTW   = tcnt * KS;

    const bf16x8 ZB = __builtin_bit_cast(bf16x8, (float4){0.f, 0.f, 0.f, 0.f});

    int idxc[WR1], idxn[WR1];
    auto load_idx = [&](int t, int (&id)[WR1]) {
#pragma unroll
        for (int r = 0; r < WR1; ++r)
            id[r] = nbr[(size_t)t * n + base + r * 16 + m16];
    };
    auto load_b = [&](int gstep, bf16x8 (&b)[WC1]) {
        const bf16* wt = W1 + (size_t)gstep * (NT1 * 512) + (cg * WC1) * 512 + lane * 8;
#pragma unroll
        for (int c = 0; c < WC1; ++c)
            b[c] = *(const bf16x8*)(wt + c * 512);
    };

    f32x4 acc1[WR1][WC1];
#pragma unroll
    for (int r = 0; r < WR1; ++r)
#pragma unroll
        for (int c = 0; c < WC1; ++c) acc1[r][c] = (f32x4){0.f, 0.f, 0.f, 0.f};

    bf16x8 aA[WR1], aB[WR1], bA[WC1], bB[WC1];

    // prologue: gathers+weights for local step 0; indices for first two taps
    load_idx(tstart, idxc);
    if (tcnt > 1) load_idx(tstart + 1, idxn);
    load_b(tstart * KS, bA);
#pragma unroll
    for (int r = 0; r < WR1; ++r) {
        bf16x8 v = ZB;
        if (idxc[r] >= 0) v = *(const bf16x8*)(X + (size_t)(unsigned)idxc[r] * CIN + quad * 8);
        aA[r] = v;
    }

    int tloc = 0, s = 0;
    auto dostep = [&](int it, bf16x8 (&aC)[WR1], bf16x8 (&bC)[WC1],
                      bf16x8 (&aN)[WR1], bf16x8 (&bN)[WC1]) {
        int s1 = s + 1, tl1 = tloc;
        bool wrap = (s1 == KS);
        if (wrap) { s1 = 0; ++tl1; }
        if (it + 1 < TOTW) {
            load_b((tstart + tl1) * KS + s1, bN);    // next-step B (reg dbuf)
#pragma unroll
            for (int r = 0; r < WR1; ++r) {          // next-step gather (depth-1)
                int id_ = wrap ? idxn[r] : idxc[r];
                bf16x8 v = ZB;
                if (id_ >= 0) v = *(const bf16x8*)(X + (size_t)(unsigned)id_ * CIN + s1 * 32 + quad * 8);
                aN[r] = v;
            }
        }
        __builtin_amdgcn_s_setprio(1);
#pragma unroll
        for (int r = 0; r < WR1; ++r)
#pragma unroll
            for (int c = 0; c < WC1; ++c)
                acc1[r][c] = __builtin_amdgcn_mfma_f32_16x16x32_bf16(aC[r], bC[c], acc1[r][c], 0, 0, 0);
        __builtin_amdgcn_s_setprio(0);
        if (wrap) {
#pragma unroll
            for (int r = 0; r < WR1; ++r) idxc[r] = idxn[r];
            if (tloc + 2 < tcnt) load_idx(tstart + tloc + 2, idxn);
        }
        tloc = tl1; s = s1;
    };

    for (int it = 0; it < TOTW; it += 2) {
        dostep(it, aA, bA, aB, bB);
        if (it + 1 < TOTW) dostep(it + 1, aB, bB, aA, bA);
    }

    // ---- cross-wave tap reduction (NP passes, 1 col-frag each) -> Lt ----
    constexpr int SLICE = RW / 4;            // rows summed per wave
#pragma unroll
    for (int p = 0; p < NP; ++p) {
        __syncthreads();                     // converge / WAR on PR
        float* Pw = PR + tg * (RW * PCW);
#pragma unroll
        for (int r = 0; r < WR1; ++r)
#pragma unroll
            for (int i = 0; i < 4; ++i)
                Pw[(r * 16 + quad * 4 + i) * PCW + cg * 16 + m16] = acc1[r][p][i];
        __syncthreads();
#pragma unroll
        for (int e = lane; e < SLICE * CPT; e += 64) {
            int row   = wv * SLICE + e / CPT;
            int colsl = e & (CPT - 1);
            float v = 0.f;
#pragma unroll
            for (int g = 0; g < TW; ++g)
                v += PR[(g * RW + row) * PCW + colsl];
            int col = ((colsl >> 4) * WC1 + p) * 16 + (colsl & 15);
            v = v * sc1[col] + sh1[col];
            v = v > 0.f ? v : 0.f;
            Lt[row * LS1 + col] = (bf16)v;
        }
    }
    __syncthreads();                         // Lt complete

    // ---- dense stage 2: wave -> (row group, col group) ----
    constexpr int NT2  = C2 / 16;
    constexpr int DRW  = RW / 16 >= 4 ? 4 : RW / 16;  // 4 (RW=64) or 2 (RW=32)
    constexpr int NCG  = 4 / DRW;                     // col groups: 1 or 2
    constexpr int WC2g = NT2 / NCG;
    constexpr int KS2  = C1 / 32;
    const int wr  = wv % DRW;
    const int wcg = wv / DRW;

    f32x4 acc2[WC2g];
#pragma unroll
    for (int c = 0; c < WC2g; ++c) acc2[c] = (f32x4){0.f, 0.f, 0.f, 0.f};

#pragma unroll
    for (int s2 = 0; s2 < KS2; ++s2) {
        bf16x8 a = *(const bf16x8*)(&Lt[(wr * 16 + m16) * LS1 + s2 * 32 + quad * 8]);
        bf16x8 bw[WC2g];
#pragma unroll
        for (int c = 0; c < WC2g; ++c)
            bw[c] = *(const bf16x8*)(W2 + ((s2 * NT2 + wcg * WC2g + c) * 512 + lane * 8));
#pragma unroll
        for (int c = 0; c < WC2g; ++c)
            acc2[c] = __builtin_amdgcn_mfma_f32_16x16x32_bf16(a, bw[c], acc2[c], 0, 0, 0);
    }

    if constexpr (C3 == 0) {
#pragma unroll
        for (int c = 0; c < WC2g; ++c) {
            int col = (wcg * WC2g + c) * 16 + m16;
            float sc = sc2[col], sh = sh2[col];
            int row0 = base + wr * 16 + quad * 4;
#pragma unroll
            for (int i = 0; i < 4; ++i) {
                float v = acc2[c][i] * sc + sh;
                v = v > 0.f ? v : 0.f;
                size_t off = (size_t)(row0 + i) * ystride + yoff + col;
                if (Yf) Yf[off] = v;
                else    Y[off] = (bf16)v;
            }
        }
    } else {
        // ---- stage-2 epilogue -> Lt2 (aliases dead PR region) ----
#pragma unroll
        for (int c = 0; c < WC2g; ++c) {
            int col = (wcg * WC2g + c) * 16 + m16;
            float sc = sc2[col], sh = sh2[col];
            int row0 = wr * 16 + quad * 4;
#pragma unroll
            for (int i = 0; i < 4; ++i) {
                float v = acc2[c][i] * sc + sh;
                v = v > 0.f ? v : 0.f;
                Lt2[(row0 + i) * LS2 + col] = (bf16)v;
            }
        }
        __syncthreads();                     // Lt2 complete

        constexpr int C3v  = (C3 > 0) ? C3 : 16;
        constexpr int NT3  = C3v / 16;
        constexpr int WC3g = NT3 / NCG;
        constexpr int KS3  = C2 / 32;

        f32x4 acc3[WC3g];
#pragma unroll
        for (int c = 0; c < WC3g; ++c) acc3[c] = (f32x4){0.f, 0.f, 0.f, 0.f};

#pragma unroll
        for (int s3 = 0; s3 < KS3; ++s3) {
            bf16x8 a = *(const bf16x8*)(&Lt2[(wr * 16 + m16) * LS2 + s3 * 32 + quad * 8]);
            bf16x8 bw[WC3g];
#pragma unroll
            for (int c = 0; c < WC3g; ++c)
                bw[c] = *(const bf16x8*)(W3 + ((s3 * NT3 + wcg * WC3g + c) * 512 + lane * 8));
#pragma unroll
            for (int c = 0; c < WC3g; ++c)
                acc3[c] = __builtin_amdgcn_mfma_f32_16x16x32_bf16(a, bw[c], acc3[c], 0, 0, 0);
        }

#pragma unroll
        for (int c = 0; c < WC3g; ++c) {
            int col = (wcg * WC3g + c) * 16 + m16;
            float sc = sc3[col], sh = sh3[col];
            int row0 = base + wr * 16 + quad * 4;
#pragma unroll
            for (int i = 0; i < 4; ++i) {
                float v = acc3[c][i] * sc + sh;
                v = v > 0.f ? v : 0.f;
                size_t off = (size_t)(row0 + i) * ystride + yoff + col;
                if (Yf) Yf[off] = v;
                else    Y[off] = (bf16)v;
            }
        }
    }
}

// ---------------------------------------------------------------------------
// z[:, 64:96] = sanitize(y2[align_idx])  (features_at_coordinates + concat)
// ---------------------------------------------------------------------------
__global__ void concat_kernel(const bf16* __restrict__ y2, const int* __restrict__ align,
                              bf16* __restrict__ z, int n) {
    int e = blockIdx.x * 256 + threadIdx.x;   // over n*32
    if (e >= n * 32) return;
    int i = e >> 5, c = e & 31;
    int a = align[i];
    float v = (float)y2[(size_t)a * 32 + c];
    unsigned u = __builtin_bit_cast(unsigned, v);
    if ((u & 0x7f800000u) == 0x7f800000u) v = 0.f;   // NaN/Inf -> 0
    z[(size_t)i * 96 + 64 + c] = (bf16)v;
}

// ---------------------------------------------------------------------------
extern "C" void kernel_launch(void* const* d_in, const int* in_sizes, int n_in,
                              void* d_out, int out_size, void* d_ws, size_t ws_size,
                              hipStream_t stream) {
    const float* feat3d = (const float*)d_in[0];
    const float* feat2d = (const float*)d_in[1];
    const float* Wsrc[11];
    for (int i = 0; i < 11; ++i) Wsrc[i] = (const float*)d_in[2 + i];
    const float* bn[22];
    for (int i = 0; i < 22; ++i) bn[i] = (const float*)d_in[13 + i];
    const int* nbr   = (const int*)d_in[35];
    const int* align = (const int*)d_in[36];
    float* out = (float*)d_out;

    const int n = in_sizes[0] / 96;   // 80000, divisible by 64 and 32

    // workspace layout
    char* ws = (char*)d_ws;
    size_t off = 0;
    auto alloc = [&](size_t bytes) -> void* {
        void* p = ws + off;
        off = (off + bytes + 255) & ~(size_t)255;
        return p;
    };
    bf16* F3 = (bf16*)alloc((size_t)n * 96 * 2);
    bf16* F2 = (bf16*)alloc((size_t)n * 256 * 2);
    static const int wt_taps[11] = {27, 1, 27, 1, 27, 1, 27, 1, 27, 1, 1};
    static const int wt_cin[11]  = {96, 64, 64, 64, 256, 64, 64, 32, 96, 128, 128};
    static const int wt_cout[11] = {64, 64, 64, 64, 64, 64, 32, 32, 128, 128, 128};
    bf16* Wf[11];
    for (int i = 0; i < 11; ++i)
        Wf[i] = (bf16*)alloc((size_t)wt_taps[i] * wt_cin[i] * wt_cout[i] * 2);
    bf16* tA = (bf16*)alloc((size_t)n * 64 * 2);
    bf16* tB = (bf16*)alloc((size_t)n * 64 * 2);
    bf16* y2 = (bf16*)alloc((size_t)n * 32 * 2);
    bf16* z  = (bf16*)alloc((size_t)n * 96 * 2);

    // ---- prep: converts + weight swizzles ----
    f2b_kernel<<<(n * 96 / 4 + 255) / 256, 256, 0, stream>>>(feat3d, F3, n * 96 / 4);
    f2b_kernel<<<(n * 256 / 4 + 255) / 256, 256, 0, stream>>>(feat2d, F2, n * 256 / 4);
    for (int i = 0; i < 11; ++i) {
        int total = wt_taps[i] * wt_cin[i] * wt_cout[i];
        swz_kernel<<<(total + 255) / 256, 256, 0, stream>>>(Wsrc[i], Wf[i], wt_cin[i], wt_cout[i], total);
    }

    const int GB64 = n / 64;   // 1250 blocks x 4 tap-split waves
    const int GB32 = n / 32;   // 2500 blocks (c-layer: 2 tap x 2 col waves)

    // ---- 3D branch: (a1+a2), (a3+a4) ----
    layer_kernel<96, 64, 27, 64, 0><<<GB64, 256, 0, stream>>>(
        F3, Wf[0], Wf[1], nullptr, nbr,
        bn[0], bn[1], bn[2], bn[3], nullptr, nullptr,
        tB, nullptr, 64, 0, n, GB64);
    layer_kernel<64, 64, 27, 64, 0><<<GB64, 256, 0, stream>>>(
        tB, Wf[2], Wf[3], nullptr, nbr,
        bn[4], bn[5], bn[6], bn[7], nullptr, nullptr,
        z, nullptr, 96, 0, n, GB64);               // x3 -> z[:,0:64]

    // ---- 2D branch: (b1+b2), (b3+b4) ----
    layer_kernel<256, 64, 27, 64, 0><<<GB64, 256, 0, stream>>>(
        F2, Wf[4], Wf[5], nullptr, nbr,
        bn[8], bn[9], bn[10], bn[11], nullptr, nullptr,
        tA, nullptr, 64, 0, n, GB64);
    layer_kernel<64, 32, 27, 32, 0><<<GB64, 256, 0, stream>>>(
        tA, Wf[6], Wf[7], nullptr, nbr,
        bn[12], bn[13], bn[14], bn[15], nullptr, nullptr,
        y2, nullptr, 32, 0, n, GB64);

    // ---- align gather + concat into z[:,64:96] ----
    concat_kernel<<<(n * 32 + 255) / 256, 256, 0, stream>>>(y2, align, z, n);

    // ---- fusion: (c1+c2+c3) ----
    layer_kernel<96, 128, 27, 128, 128><<<GB32, 256, 0, stream>>>(
        z, Wf[8], Wf[9], Wf[10], nbr,
        bn[16], bn[17], bn[18], bn[19], bn[20], bn[21],
        nullptr, out, 128, 0, n, GB32);
}